// Round 1
// baseline (257.803 us; speedup 1.0000x reference)
//
#include <hip/hip_runtime.h>
#include <hip/hip_bf16.h>
#include <math.h>

#define B_    16
#define C_    512
#define N_    1024
#define G_    8
#define HEADS 4
#define CH    128
#define EPS   1e-5f

typedef __attribute__((ext_vector_type(8))) short short8;
typedef __attribute__((ext_vector_type(4))) float f32x4;

__device__ __forceinline__ float bf2f(unsigned short u) {
  union { unsigned int i; float f; } x; x.i = ((unsigned int)u) << 16; return x.f;
}
__device__ __forceinline__ unsigned short f2bf(float f) {
  union { float f; unsigned int i; } x; x.f = f;
  unsigned int r = x.i + 0x7FFFu + ((x.i >> 16) & 1u);
  return (unsigned short)(r >> 16);
}

// ---------------- GroupNorm stats: one block per (b, g) ----------------
__global__ __launch_bounds__(256) void gn_stats(const float* __restrict__ x,
                                                float* __restrict__ stats) {
  int bg = blockIdx.x;  // 0..127
  const float4* p4 = (const float4*)(x + (size_t)bg * (C_ / G_) * N_);
  const int n4 = (C_ / G_) * N_ / 4;  // 16384
  float s = 0.f, ss = 0.f;
  for (int i = threadIdx.x; i < n4; i += 256) {
    float4 v = p4[i];
    s  += v.x + v.y + v.z + v.w;
    ss += v.x * v.x + v.y * v.y + v.z * v.z + v.w * v.w;
  }
  for (int o = 32; o; o >>= 1) { s += __shfl_down(s, o); ss += __shfl_down(ss, o); }
  __shared__ float ls[4], lss[4];
  int wid = threadIdx.x >> 6, lane = threadIdx.x & 63;
  if (lane == 0) { ls[wid] = s; lss[wid] = ss; }
  __syncthreads();
  if (threadIdx.x == 0) {
    float S = ls[0] + ls[1] + ls[2] + ls[3];
    float SS = lss[0] + lss[1] + lss[2] + lss[3];
    const float inv = 1.f / ((C_ / G_) * N_);
    float mean = S * inv;
    float var = SS * inv - mean * mean;
    stats[bg * 2]     = mean;
    stats[bg * 2 + 1] = rsqrtf(var + EPS);
  }
}

// ---------------- weight conversion fp32 -> bf16 ----------------
__global__ __launch_bounds__(256) void conv_w(const float* __restrict__ q, const float* __restrict__ k,
                                              const float* __restrict__ v, const float* __restrict__ p,
                                              unsigned short* __restrict__ dst) {
  const int n = C_ * C_;
  int i = blockIdx.x * 256 + threadIdx.x;
  if (i < n) {
    dst[i]         = f2bf(q[i]);
    dst[n + i]     = f2bf(k[i]);
    dst[2 * n + i] = f2bf(v[i]);
    dst[3 * n + i] = f2bf(p[i]);
  }
}

// ---------------- GroupNorm apply + transpose -> hT (B, N, C) bf16 ----------------
__global__ __launch_bounds__(256) void gn_apply(const float* __restrict__ x,
                                                const float* __restrict__ stats,
                                                const float* __restrict__ gw,
                                                const float* __restrict__ gb,
                                                unsigned short* __restrict__ hT) {
  __shared__ float T[64][65];
  int b = blockIdx.z, c0 = blockIdx.y * 64, n0 = blockIdx.x * 64;
  int g = c0 / (C_ / G_);
  float mean = stats[(b * G_ + g) * 2], rstd = stats[(b * G_ + g) * 2 + 1];
  int t = threadIdx.x;
  for (int it = 0; it < 4; it++) {
    int L = it * 256 + t;
    int cc = L >> 4, nf = L & 15;
    float4 v = *(const float4*)&x[((size_t)b * C_ + c0 + cc) * N_ + n0 + nf * 4];
    float sw = gw[c0 + cc] * rstd, sb = gb[c0 + cc] - mean * sw;
    T[cc][nf * 4 + 0] = v.x * sw + sb;
    T[cc][nf * 4 + 1] = v.y * sw + sb;
    T[cc][nf * 4 + 2] = v.z * sw + sb;
    T[cc][nf * 4 + 3] = v.w * sw + sb;
  }
  __syncthreads();
  for (int it = 0; it < 4; it++) {
    int L = it * 256 + t;
    int nn = L >> 4, cv = L & 15;
    ushort4 o;
    o.x = f2bf(T[cv * 4 + 0][nn]);
    o.y = f2bf(T[cv * 4 + 1][nn]);
    o.z = f2bf(T[cv * 4 + 2][nn]);
    o.w = f2bf(T[cv * 4 + 3][nn]);
    *(ushort4*)&hT[((size_t)b * N_ + n0 + nn) * C_ + c0 + cv * 4] = o;
  }
}

// ---------------- TN GEMM: D[i][j] = sum_k A[i][k] * Bt[j][k] ----------------
// A: [M][K] row-major (K-contiguous), Bt: [Ncols][K] row-major (K-contiguous)
template <bool OUT_BF16, bool BIAS_I, bool RESID>
__global__ __launch_bounds__(256) void gemm_tn(const unsigned short* __restrict__ A,
                                               const unsigned short* __restrict__ Bt,
                                               const float* __restrict__ bias,
                                               const float* __restrict__ resid,
                                               void* __restrict__ out,
                                               int M, int Ncols, int K,
                                               long aBS, long bBS, long oBS) {
  __shared__ __align__(16) unsigned short As[128][72];
  __shared__ __align__(16) unsigned short Bs[128][72];
  int b = blockIdx.z;
  const unsigned short* Ab = A + (size_t)b * aBS;
  const unsigned short* Bb = Bt + (size_t)b * bBS;
  int i0 = blockIdx.y * 128, j0 = blockIdx.x * 128;
  int t = threadIdx.x;
  int w = t >> 6, l = t & 63;
  int wi = (w >> 1) * 64, wj = (w & 1) * 64;
  int lr = l & 15, lk = (l >> 4) * 8;

  f32x4 acc[4][4];
  const f32x4 zf = {0.f, 0.f, 0.f, 0.f};
#pragma unroll
  for (int m = 0; m < 4; m++)
#pragma unroll
    for (int n = 0; n < 4; n++) acc[m][n] = zf;

  for (int kt = 0; kt < K; kt += 64) {
    __syncthreads();
#pragma unroll
    for (int it = 0; it < 4; it++) {
      int L = it * 256 + t;
      int row = L >> 3, c8 = (L & 7) * 8;
      *(uint4*)&As[row][c8] = *(const uint4*)&Ab[(size_t)(i0 + row) * K + kt + c8];
      *(uint4*)&Bs[row][c8] = *(const uint4*)&Bb[(size_t)(j0 + row) * K + kt + c8];
    }
    __syncthreads();
#pragma unroll
    for (int ks = 0; ks < 64; ks += 32) {
      short8 af[4], bf[4];
#pragma unroll
      for (int m = 0; m < 4; m++) af[m] = *(const short8*)&As[wi + m * 16 + lr][ks + lk];
#pragma unroll
      for (int n = 0; n < 4; n++) bf[n] = *(const short8*)&Bs[wj + n * 16 + lr][ks + lk];
#pragma unroll
      for (int m = 0; m < 4; m++)
#pragma unroll
        for (int n = 0; n < 4; n++)
          acc[m][n] = __builtin_amdgcn_mfma_f32_16x16x32_bf16(af[m], bf[n], acc[m][n], 0, 0, 0);
    }
  }

  int rbase = (l >> 4) * 4;
#pragma unroll
  for (int m = 0; m < 4; m++) {
    int ig = i0 + wi + m * 16 + rbase;
#pragma unroll
    for (int n = 0; n < 4; n++) {
      int jg = j0 + wj + n * 16 + lr;
#pragma unroll
      for (int r = 0; r < 4; r++) {
        float vv = acc[m][n][r];
        vv += BIAS_I ? bias[ig + r] : bias[jg];
        size_t oidx = (size_t)b * oBS + (size_t)(ig + r) * Ncols + jg;
        if (RESID) vv += resid[oidx];
        if (OUT_BF16) ((unsigned short*)out)[oidx] = f2bf(vv);
        else ((float*)out)[oidx] = vv;
      }
    }
  }
}

// ---------------- fused flash attention ----------------
// qT,kT: (B, N, C) bf16; v: (B, C, N) bf16; out aoT: (B, N, C) bf16
__global__ __launch_bounds__(256) void attn_kernel(const unsigned short* __restrict__ qT,
                                                   const unsigned short* __restrict__ kT,
                                                   const unsigned short* __restrict__ v,
                                                   unsigned short* __restrict__ aoT) {
  __shared__ __align__(16) unsigned short Ks[64][136];
  __shared__ __align__(16) unsigned short Vs[128][72];
  __shared__ __align__(16) unsigned short Ps[4][16][72];
  int bh = blockIdx.y;
  int b = bh >> 2, hd = bh & 3;
  int c0h = hd * CH;
  int qt = blockIdx.x;
  int t = threadIdx.x, w = t >> 6, l = t & 63;
  int lr = l & 15, lk = (l >> 4) * 8;
  int qbase = qt * 64 + w * 16;
  const float scale = 0.08838834764831845f;

  short8 qf[4];
#pragma unroll
  for (int ks = 0; ks < 4; ks++)
    qf[ks] = *(const short8*)&qT[((size_t)b * N_ + qbase + lr) * C_ + c0h + ks * 32 + lk];

  f32x4 o[8];
  const f32x4 zf = {0.f, 0.f, 0.f, 0.f};
#pragma unroll
  for (int cs = 0; cs < 8; cs++) o[cs] = zf;
  float mrow[4] = {-INFINITY, -INFINITY, -INFINITY, -INFINITY};
  float lrow[4] = {0.f, 0.f, 0.f, 0.f};

  for (int mt = 0; mt < N_; mt += 64) {
    __syncthreads();
#pragma unroll
    for (int it = 0; it < 4; it++) {  // K tile: 64 rows x 128 c
      int L = it * 256 + t;
      int row = L >> 4, c8 = (L & 15) * 8;
      *(uint4*)&Ks[row][c8] = *(const uint4*)&kT[((size_t)b * N_ + mt + row) * C_ + c0h + c8];
    }
#pragma unroll
    for (int it = 0; it < 4; it++) {  // V tile: 128 rows(c) x 64 m
      int L = it * 256 + t;
      int row = L >> 3, m8 = (L & 7) * 8;
      *(uint4*)&Vs[row][m8] = *(const uint4*)&v[((size_t)b * C_ + c0h + row) * N_ + mt + m8];
    }
    __syncthreads();

    f32x4 s[4];
#pragma unroll
    for (int m = 0; m < 4; m++) s[m] = zf;
#pragma unroll
    for (int ks = 0; ks < 4; ks++) {
      short8 bfr[4];
#pragma unroll
      for (int m = 0; m < 4; m++) bfr[m] = *(const short8*)&Ks[m * 16 + lr][ks * 32 + lk];
#pragma unroll
      for (int m = 0; m < 4; m++)
        s[m] = __builtin_amdgcn_mfma_f32_16x16x32_bf16(qf[ks], bfr[m], s[m], 0, 0, 0);
    }

    float mx[4], alpha[4], rsum[4];
#pragma unroll
    for (int r = 0; r < 4; r++) {
      float m0 = fmaxf(fmaxf(s[0][r], s[1][r]), fmaxf(s[2][r], s[3][r])) * scale;
      for (int o_ = 1; o_ < 16; o_ <<= 1) m0 = fmaxf(m0, __shfl_xor(m0, o_));
      mx[r] = m0;
      float mn = fmaxf(mrow[r], mx[r]);
      alpha[r] = __expf(mrow[r] - mn);
      mrow[r] = mn;
      rsum[r] = 0.f;
    }
#pragma unroll
    for (int m = 0; m < 4; m++) {
#pragma unroll
      for (int r = 0; r < 4; r++) {
        float p = __expf(s[m][r] * scale - mrow[r]);
        rsum[r] += p;
        Ps[w][(l >> 4) * 4 + r][m * 16 + lr] = f2bf(p);
      }
    }
#pragma unroll
    for (int r = 0; r < 4; r++) {
      float sm = rsum[r];
      for (int o_ = 1; o_ < 16; o_ <<= 1) sm += __shfl_xor(sm, o_);
      lrow[r] = lrow[r] * alpha[r] + sm;
    }
#pragma unroll
    for (int cs = 0; cs < 8; cs++)
#pragma unroll
      for (int r = 0; r < 4; r++) o[cs][r] *= alpha[r];

#pragma unroll
    for (int ks2 = 0; ks2 < 2; ks2++) {
      short8 pf = *(const short8*)&Ps[w][lr][ks2 * 32 + lk];
#pragma unroll
      for (int cs = 0; cs < 8; cs++) {
        short8 vf = *(const short8*)&Vs[cs * 16 + lr][ks2 * 32 + lk];
        o[cs] = __builtin_amdgcn_mfma_f32_16x16x32_bf16(pf, vf, o[cs], 0, 0, 0);
      }
    }
  }

#pragma unroll
  for (int r = 0; r < 4; r++) {
    int n = qbase + (l >> 4) * 4 + r;
    float inv = 1.f / lrow[r];
#pragma unroll
    for (int cs = 0; cs < 8; cs++)
      aoT[((size_t)b * N_ + n) * C_ + c0h + cs * 16 + lr] = f2bf(o[cs][r] * inv);
  }
}

extern "C" void kernel_launch(void* const* d_in, const int* in_sizes, int n_in,
                              void* d_out, int out_size, void* d_ws, size_t ws_size,
                              hipStream_t stream) {
  const float* x  = (const float*)d_in[0];
  const float* nw = (const float*)d_in[1];
  const float* nb = (const float*)d_in[2];
  const float* qw = (const float*)d_in[3];
  const float* qb = (const float*)d_in[4];
  const float* kw = (const float*)d_in[5];
  const float* kb = (const float*)d_in[6];
  const float* vw = (const float*)d_in[7];
  const float* vb = (const float*)d_in[8];
  const float* pw = (const float*)d_in[9];
  const float* pb = (const float*)d_in[10];

  char* ws = (char*)d_ws;
  unsigned short* wbf  = (unsigned short*)ws;                  // 4 x 512*512 bf16 (q,k,v,p)
  float*          stats = (float*)(ws + 0x200000);             // 256 floats
  unsigned short* hT   = (unsigned short*)(ws + 0x201000);     // 16 MiB (B,N,C)
  unsigned short* qT   = (unsigned short*)(ws + 0x1201000);
  unsigned short* kT   = (unsigned short*)(ws + 0x2201000);
  unsigned short* vv   = (unsigned short*)(ws + 0x3201000);    // (B,C,N)
  unsigned short* aoT  = hT;                                   // reuse after h consumed

  const long NC = (long)N_ * C_;
  const int n_w = C_ * C_;

  gn_stats<<<B_ * G_, 256, 0, stream>>>(x, stats);
  conv_w<<<n_w / 256, 256, 0, stream>>>(qw, kw, vw, pw, wbf);
  gn_apply<<<dim3(N_ / 64, C_ / 64, B_), 256, 0, stream>>>(x, stats, nw, nb, hT);

  // q: qT[b][n][o] = sum_c hT[n][c] qw[o][c] + qb[o]
  gemm_tn<true, false, false><<<dim3(C_ / 128, N_ / 128, B_), 256, 0, stream>>>(
      hT, wbf, qb, nullptr, qT, N_, C_, C_, NC, 0, NC);
  // k
  gemm_tn<true, false, false><<<dim3(C_ / 128, N_ / 128, B_), 256, 0, stream>>>(
      hT, wbf + n_w, kb, nullptr, kT, N_, C_, C_, NC, 0, NC);
  // v: v[b][o][n] = sum_c vw[o][c] hT[n][c] + vb[o]
  gemm_tn<true, true, false><<<dim3(N_ / 128, C_ / 128, B_), 256, 0, stream>>>(
      wbf + 2 * n_w, hT, vb, nullptr, vv, C_, N_, C_, 0, NC, NC);

  attn_kernel<<<dim3(N_ / 64, B_ * HEADS), 256, 0, stream>>>(qT, kT, vv, aoT);

  // p: out[b][o][n] = sum_c pw[o][c] ao[c][n] + pb[o] + x
  gemm_tn<false, true, true><<<dim3(N_ / 128, C_ / 128, B_), 256, 0, stream>>>(
      wbf + 3 * n_w, aoT, pb, x, d_out, C_, N_, C_, 0, NC, NC);
}

// Round 2
// 160.733 us; speedup vs baseline: 1.6039x; 1.6039x over previous
//
#include <hip/hip_runtime.h>
#include <hip/hip_bf16.h>
#include <math.h>

#define B_    16
#define C_    512
#define N_    1024
#define G_    8
#define HEADS 4
#define CH    128
#define EPS   1e-5f

typedef __attribute__((ext_vector_type(8))) short short8;
typedef __attribute__((ext_vector_type(4))) float f32x4;
typedef __attribute__((ext_vector_type(16))) float f32x16;
typedef __attribute__((ext_vector_type(4))) int i32x4;

__device__ __forceinline__ unsigned short f2bf(float f) {
  union { float f; unsigned int i; } x; x.f = f;
  unsigned int r = x.i + 0x7FFFu + ((x.i >> 16) & 1u);
  return (unsigned short)(r >> 16);
}

// ---------------- GroupNorm stats: one block per (b, g) ----------------
__global__ __launch_bounds__(256) void gn_stats(const float* __restrict__ x,
                                                float* __restrict__ stats) {
  int bg = blockIdx.x;  // 0..127
  const float4* p4 = (const float4*)(x + (size_t)bg * (C_ / G_) * N_);
  const int n4 = (C_ / G_) * N_ / 4;  // 16384
  float s = 0.f, ss = 0.f;
  for (int i = threadIdx.x; i < n4; i += 256) {
    float4 v = p4[i];
    s  += v.x + v.y + v.z + v.w;
    ss += v.x * v.x + v.y * v.y + v.z * v.z + v.w * v.w;
  }
  for (int o = 32; o; o >>= 1) { s += __shfl_down(s, o); ss += __shfl_down(ss, o); }
  __shared__ float ls[4], lss[4];
  int wid = threadIdx.x >> 6, lane = threadIdx.x & 63;
  if (lane == 0) { ls[wid] = s; lss[wid] = ss; }
  __syncthreads();
  if (threadIdx.x == 0) {
    float S = ls[0] + ls[1] + ls[2] + ls[3];
    float SS = lss[0] + lss[1] + lss[2] + lss[3];
    const float inv = 1.f / ((C_ / G_) * N_);
    float mean = S * inv;
    float var = SS * inv - mean * mean;
    stats[bg * 2]     = mean;
    stats[bg * 2 + 1] = rsqrtf(var + EPS);
  }
}

// ---------------- weight conversion fp32 -> bf16 ----------------
__global__ __launch_bounds__(256) void conv_w(const float* __restrict__ q, const float* __restrict__ k,
                                              const float* __restrict__ v, const float* __restrict__ p,
                                              unsigned short* __restrict__ dst) {
  const int n = C_ * C_;
  int i = blockIdx.x * 256 + threadIdx.x;
  if (i < n) {
    dst[i]         = f2bf(q[i]);
    dst[n + i]     = f2bf(k[i]);
    dst[2 * n + i] = f2bf(v[i]);
    dst[3 * n + i] = f2bf(p[i]);
  }
}

// ---------------- GroupNorm apply + transpose -> hT (B, N, C) bf16 ----------------
__global__ __launch_bounds__(256) void gn_apply(const float* __restrict__ x,
                                                const float* __restrict__ stats,
                                                const float* __restrict__ gw,
                                                const float* __restrict__ gb,
                                                unsigned short* __restrict__ hT) {
  __shared__ float T[64][65];
  int b = blockIdx.z, c0 = blockIdx.y * 64, n0 = blockIdx.x * 64;
  int g = c0 / (C_ / G_);
  float mean = stats[(b * G_ + g) * 2], rstd = stats[(b * G_ + g) * 2 + 1];
  int t = threadIdx.x;
  for (int it = 0; it < 4; it++) {
    int L = it * 256 + t;
    int cc = L >> 4, nf = L & 15;
    float4 v = *(const float4*)&x[((size_t)b * C_ + c0 + cc) * N_ + n0 + nf * 4];
    float sw = gw[c0 + cc] * rstd, sb = gb[c0 + cc] - mean * sw;
    T[cc][nf * 4 + 0] = v.x * sw + sb;
    T[cc][nf * 4 + 1] = v.y * sw + sb;
    T[cc][nf * 4 + 2] = v.z * sw + sb;
    T[cc][nf * 4 + 3] = v.w * sw + sb;
  }
  __syncthreads();
  for (int it = 0; it < 4; it++) {
    int L = it * 256 + t;
    int nn = L >> 4, cv = L & 15;
    ushort4 o;
    o.x = f2bf(T[cv * 4 + 0][nn]);
    o.y = f2bf(T[cv * 4 + 1][nn]);
    o.z = f2bf(T[cv * 4 + 2][nn]);
    o.w = f2bf(T[cv * 4 + 3][nn]);
    *(ushort4*)&hT[((size_t)b * N_ + n0 + nn) * C_ + c0 + cv * 4] = o;
  }
}

// ---------------- TN GEMM: D[i][j] = sum_k A[i][k] * Bt[j][k] ----------------
template <bool OUT_BF16, bool BIAS_I, bool RESID>
__global__ __launch_bounds__(256) void gemm_tn(const unsigned short* __restrict__ A,
                                               const unsigned short* __restrict__ Bt,
                                               const float* __restrict__ bias,
                                               const float* __restrict__ resid,
                                               void* __restrict__ out,
                                               int M, int Ncols, int K,
                                               long aBS, long bBS, long oBS) {
  __shared__ __align__(16) unsigned short As[128][72];
  __shared__ __align__(16) unsigned short Bs[128][72];
  int b = blockIdx.z;
  const unsigned short* Ab = A + (size_t)b * aBS;
  const unsigned short* Bb = Bt + (size_t)b * bBS;
  int i0 = blockIdx.y * 128, j0 = blockIdx.x * 128;
  int t = threadIdx.x;
  int w = t >> 6, l = t & 63;
  int wi = (w >> 1) * 64, wj = (w & 1) * 64;
  int lr = l & 15, lk = (l >> 4) * 8;

  f32x4 acc[4][4];
  const f32x4 zf = {0.f, 0.f, 0.f, 0.f};
#pragma unroll
  for (int m = 0; m < 4; m++)
#pragma unroll
    for (int n = 0; n < 4; n++) acc[m][n] = zf;

  for (int kt = 0; kt < K; kt += 64) {
    __syncthreads();
#pragma unroll
    for (int it = 0; it < 4; it++) {
      int L = it * 256 + t;
      int row = L >> 3, c8 = (L & 7) * 8;
      *(uint4*)&As[row][c8] = *(const uint4*)&Ab[(size_t)(i0 + row) * K + kt + c8];
      *(uint4*)&Bs[row][c8] = *(const uint4*)&Bb[(size_t)(j0 + row) * K + kt + c8];
    }
    __syncthreads();
#pragma unroll
    for (int ks = 0; ks < 64; ks += 32) {
      short8 af[4], bf[4];
#pragma unroll
      for (int m = 0; m < 4; m++) af[m] = *(const short8*)&As[wi + m * 16 + lr][ks + lk];
#pragma unroll
      for (int n = 0; n < 4; n++) bf[n] = *(const short8*)&Bs[wj + n * 16 + lr][ks + lk];
#pragma unroll
      for (int m = 0; m < 4; m++)
#pragma unroll
        for (int n = 0; n < 4; n++)
          acc[m][n] = __builtin_amdgcn_mfma_f32_16x16x32_bf16(af[m], bf[n], acc[m][n], 0, 0, 0);
    }
  }

  int rbase = (l >> 4) * 4;
#pragma unroll
  for (int m = 0; m < 4; m++) {
    int ig = i0 + wi + m * 16 + rbase;
#pragma unroll
    for (int n = 0; n < 4; n++) {
      int jg = j0 + wj + n * 16 + lr;
#pragma unroll
      for (int r = 0; r < 4; r++) {
        float vv = acc[m][n][r];
        vv += BIAS_I ? bias[ig + r] : bias[jg];
        size_t oidx = (size_t)b * oBS + (size_t)(ig + r) * Ncols + jg;
        if (RESID) vv += resid[oidx];
        if (OUT_BF16) ((unsigned short*)out)[oidx] = f2bf(vv);
        else ((float*)out)[oidx] = vv;
      }
    }
  }
}

// ---------------- fused flash attention, 8-warp 32x32 swapped-QK^T ----------------
// qT,kT: (B, N, C) bf16; v: (B, C, N) bf16; out aoT: (B, N, C) bf16
__global__ __launch_bounds__(512, 2) void attn_kernel(const unsigned short* __restrict__ qT,
                                                      const unsigned short* __restrict__ kT,
                                                      const unsigned short* __restrict__ v,
                                                      unsigned short* __restrict__ aoT) {
  // K tile: [64 kv][128 c], V tile: [128 c][64 kv]; XOR-swizzled (gcol ^= row&7), dbl-buffered
  __shared__ __align__(16) unsigned short Ks[2][64 * 128];
  __shared__ __align__(16) unsigned short Vs[2][128 * 64];
  const int t = threadIdx.x, w = t >> 6, l = t & 63;
  const int h = l >> 5, l31 = l & 31, l7 = l & 7;
  const int bh = blockIdx.y, b = bh >> 2, hd = bh & 3, c0h = hd * CH;
  const int qg = blockIdx.x * 256 + w * 32 + l31;
  const float sc2 = 0.08838834764831845f * 1.4426950408889634f;  // scale * log2(e)
  const float THRRAW = 11.5f / sc2;                              // defer-max threshold

  // Q fragments (MFMA B-operand): qf[kc] = Q[qg][c0h + 16*kc + 8h .. +7]
  short8 qf[8];
  const unsigned short* qrow = qT + ((size_t)b * N_ + qg) * C_ + c0h;
#pragma unroll
  for (int kc = 0; kc < 8; kc++)
    qf[kc] = *(const short8*)&qrow[kc * 16 + h * 8];

  f32x16 o[4];
#pragma unroll
  for (int ct = 0; ct < 4; ct++) o[ct] = (f32x16)(0.f);
  float m = -INFINITY, lsum = 0.f;

  // stage K/V tile tt into buffer cur via global_load_lds with pre-swizzled source
  auto stage = [&](int cur, int tt) {
    int mt = tt * 64;
#pragma unroll
    for (int i = 0; i < 2; i++) {
      int seg = w * 2 + i;
      {  // K: wave covers 4 rows of 128 c (256B each)
        int row = seg * 4 + (l >> 4);
        int gc = (l & 15) ^ (row & 7);
        const unsigned short* src = kT + ((size_t)b * N_ + mt + row) * C_ + c0h + gc * 8;
        __builtin_amdgcn_global_load_lds((const __attribute__((address_space(1))) void*)src,
                                         (__attribute__((address_space(3))) void*)&Ks[cur][seg * 512],
                                         16, 0, 0);
      }
      {  // V: wave covers 8 rows of 64 kv (128B each)
        int row = seg * 8 + (l >> 3);
        int gc = (l & 7) ^ (row & 7);
        const unsigned short* src = v + ((size_t)b * C_ + c0h + row) * N_ + mt + gc * 8;
        __builtin_amdgcn_global_load_lds((const __attribute__((address_space(1))) void*)src,
                                         (__attribute__((address_space(3))) void*)&Vs[cur][seg * 512],
                                         16, 0, 0);
      }
    }
  };

  stage(0, 0);

  for (int tt = 0; tt < 16; tt++) {
    int cur = tt & 1;
    __syncthreads();  // drains vmcnt: staged tile ready; prev tile reads done
    if (tt < 15) stage(cur ^ 1, tt + 1);

    // ---- QK^T (swapped): S^T[kv][q] = sum_c K[kv][c] * Q[q][c] ----
    f32x16 st0 = (f32x16)(0.f), st1 = (f32x16)(0.f);
    const unsigned short* KsB = &Ks[cur][0];
    __builtin_amdgcn_s_setprio(1);
#pragma unroll
    for (int kc = 0; kc < 8; kc++) {
      short8 kf0 = *(const short8*)&KsB[l31 * 128 + (((2 * kc + h) ^ l7) * 8)];
      short8 kf1 = *(const short8*)&KsB[(32 + l31) * 128 + (((2 * kc + h) ^ l7) * 8)];
      st0 = __builtin_amdgcn_mfma_f32_32x32x16_bf16(kf0, qf[kc], st0, 0, 0, 0);
      st1 = __builtin_amdgcn_mfma_f32_32x32x16_bf16(kf1, qf[kc], st1, 0, 0, 0);
    }
    __builtin_amdgcn_s_setprio(0);

    // ---- in-register online softmax: lane holds 32 kv vals for q = lane&31 ----
    float pmax = st0[0];
#pragma unroll
    for (int r = 1; r < 16; r++) pmax = fmaxf(pmax, st0[r]);
#pragma unroll
    for (int r = 0; r < 16; r++) pmax = fmaxf(pmax, st1[r]);
    pmax = fmaxf(pmax, __shfl_xor(pmax, 32));

    bool defer = (pmax <= m + THRRAW);
    bool skip = __all(defer);
    float mnew = skip ? m : fmaxf(m, pmax);
    float alpha = skip ? 1.f : exp2f((m - mnew) * sc2);
    float mb = mnew * sc2;
    m = mnew;

    float ps = 0.f;
    short8 pf[4];
#pragma unroll
    for (int g = 0; g < 4; g++) {
      const int e0 = (g & 1) * 8;
      float p0, p1, p2, p3, p4, p5, p6, p7;
      if (g < 2) {
        p0 = exp2f(fmaf(st0[e0 + 0], sc2, -mb)); p1 = exp2f(fmaf(st0[e0 + 1], sc2, -mb));
        p2 = exp2f(fmaf(st0[e0 + 2], sc2, -mb)); p3 = exp2f(fmaf(st0[e0 + 3], sc2, -mb));
        p4 = exp2f(fmaf(st0[e0 + 4], sc2, -mb)); p5 = exp2f(fmaf(st0[e0 + 5], sc2, -mb));
        p6 = exp2f(fmaf(st0[e0 + 6], sc2, -mb)); p7 = exp2f(fmaf(st0[e0 + 7], sc2, -mb));
      } else {
        p0 = exp2f(fmaf(st1[e0 + 0], sc2, -mb)); p1 = exp2f(fmaf(st1[e0 + 1], sc2, -mb));
        p2 = exp2f(fmaf(st1[e0 + 2], sc2, -mb)); p3 = exp2f(fmaf(st1[e0 + 3], sc2, -mb));
        p4 = exp2f(fmaf(st1[e0 + 4], sc2, -mb)); p5 = exp2f(fmaf(st1[e0 + 5], sc2, -mb));
        p6 = exp2f(fmaf(st1[e0 + 6], sc2, -mb)); p7 = exp2f(fmaf(st1[e0 + 7], sc2, -mb));
      }
      ps += p0 + p1 + p2 + p3 + p4 + p5 + p6 + p7;
      unsigned int x, x2, y, y2;
      asm("v_cvt_pk_bf16_f32 %0, %1, %2" : "=v"(x)  : "v"(p0), "v"(p1));
      asm("v_cvt_pk_bf16_f32 %0, %1, %2" : "=v"(x2) : "v"(p2), "v"(p3));
      asm("v_cvt_pk_bf16_f32 %0, %1, %2" : "=v"(y)  : "v"(p4), "v"(p5));
      asm("v_cvt_pk_bf16_f32 %0, %1, %2" : "=v"(y2) : "v"(p6), "v"(p7));
      asm("v_permlane32_swap_b32 %0, %1" : "+v"(x), "+v"(y));
      asm("v_permlane32_swap_b32 %0, %1" : "+v"(x2), "+v"(y2));
      i32x4 pwv = {(int)x, (int)x2, (int)y, (int)y2};
      pf[g] = __builtin_bit_cast(short8, pwv);
    }
    ps += __shfl_xor(ps, 32);
    lsum = lsum * alpha + ps;

    if (!skip) {
#pragma unroll
      for (int ct = 0; ct < 4; ct++)
#pragma unroll
        for (int r = 0; r < 16; r++) o[ct][r] *= alpha;
    }

    // ---- PV: O^T[c][q] += sum_kv V[c][kv] * P[q][kv] ----
    const unsigned short* VsB = &Vs[cur][0];
    __builtin_amdgcn_s_setprio(1);
#pragma unroll
    for (int ct = 0; ct < 4; ct++) {
#pragma unroll
      for (int g = 0; g < 4; g++) {
        short8 vf = *(const short8*)&VsB[(ct * 32 + l31) * 64 + (((2 * g + h) ^ l7) * 8)];
        o[ct] = __builtin_amdgcn_mfma_f32_32x32x16_bf16(vf, pf[g], o[ct], 0, 0, 0);
      }
    }
    __builtin_amdgcn_s_setprio(0);
  }

  float rn = 1.f / lsum;
  unsigned short* orow = aoT + ((size_t)b * N_ + qg) * C_ + c0h;
#pragma unroll
  for (int ct = 0; ct < 4; ct++)
#pragma unroll
    for (int u = 0; u < 4; u++) {
      ushort4 ov;
      ov.x = f2bf(o[ct][u * 4 + 0] * rn);
      ov.y = f2bf(o[ct][u * 4 + 1] * rn);
      ov.z = f2bf(o[ct][u * 4 + 2] * rn);
      ov.w = f2bf(o[ct][u * 4 + 3] * rn);
      *(ushort4*)&orow[ct * 32 + u * 8 + h * 4] = ov;
    }
}

extern "C" void kernel_launch(void* const* d_in, const int* in_sizes, int n_in,
                              void* d_out, int out_size, void* d_ws, size_t ws_size,
                              hipStream_t stream) {
  const float* x  = (const float*)d_in[0];
  const float* nw = (const float*)d_in[1];
  const float* nb = (const float*)d_in[2];
  const float* qw = (const float*)d_in[3];
  const float* qb = (const float*)d_in[4];
  const float* kw = (const float*)d_in[5];
  const float* kb = (const float*)d_in[6];
  const float* vw = (const float*)d_in[7];
  const float* vb = (const float*)d_in[8];
  const float* pw = (const float*)d_in[9];
  const float* pb = (const float*)d_in[10];

  char* ws = (char*)d_ws;
  unsigned short* wbf  = (unsigned short*)ws;                  // 4 x 512*512 bf16 (q,k,v,p)
  float*          stats = (float*)(ws + 0x200000);             // 256 floats
  unsigned short* hT   = (unsigned short*)(ws + 0x201000);     // 16 MiB (B,N,C)
  unsigned short* qT   = (unsigned short*)(ws + 0x1201000);
  unsigned short* kT   = (unsigned short*)(ws + 0x2201000);
  unsigned short* vv   = (unsigned short*)(ws + 0x3201000);    // (B,C,N)
  unsigned short* aoT  = hT;                                   // reuse after h consumed

  const long NC = (long)N_ * C_;
  const int n_w = C_ * C_;

  gn_stats<<<B_ * G_, 256, 0, stream>>>(x, stats);
  conv_w<<<n_w / 256, 256, 0, stream>>>(qw, kw, vw, pw, wbf);
  gn_apply<<<dim3(N_ / 64, C_ / 64, B_), 256, 0, stream>>>(x, stats, nw, nb, hT);

  gemm_tn<true, false, false><<<dim3(C_ / 128, N_ / 128, B_), 256, 0, stream>>>(
      hT, wbf, qb, nullptr, qT, N_, C_, C_, NC, 0, NC);
  gemm_tn<true, false, false><<<dim3(C_ / 128, N_ / 128, B_), 256, 0, stream>>>(
      hT, wbf + n_w, kb, nullptr, kT, N_, C_, C_, NC, 0, NC);
  gemm_tn<true, true, false><<<dim3(N_ / 128, C_ / 128, B_), 256, 0, stream>>>(
      wbf + 2 * n_w, hT, vb, nullptr, vv, C_, N_, C_, 0, NC, NC);

  attn_kernel<<<dim3(N_ / 256, B_ * HEADS), 512, 0, stream>>>(qT, kT, vv, aoT);

  gemm_tn<false, true, true><<<dim3(N_ / 128, C_ / 128, B_), 256, 0, stream>>>(
      wbf + 3 * n_w, aoT, pb, x, d_out, C_, N_, C_, 0, NC, NC);
}